// Round 1
// 2222.981 us; speedup vs baseline: 1.2439x; 1.2439x over previous
//
#include <hip/hip_runtime.h>
#include <cstdint>
#include <cstddef>

// =====================================================================
// RBM Gibbs sampling, bit-exact replication of JAX-on-CPU reference.
// ROUND 11 (perf): k_sample_v rewritten h-major/dense. Old scheme was
// VALU-overhead + gather bound (47% VALUBusy, 860us): per set-h bit it
// paid ~8 VALU of addressing/extract/bound-check + an 8-segment
// scattered load to feed 4 adds. New scheme: h ascending OUTER loop,
// W[c,h,v] row loaded ONCE fully coalesced (orig layout, Wv pre-pass
// dropped) and shared by 8 b's per wave held in registers:
//   acc[b] = fma(w, f_b, acc[b]),  f_b = (float)bit_h(b) in {0,1}.
// Bit-exact vs frozen "K=256 sequential chain": fma(w,1,acc) =
// round(acc+w) = v_add; fma(w,0,acc) = acc + (+/-0) = acc bitwise
// (acc never -0.0; product exact => fused or unfused identical).
// Per-c running first-max argmax (c ascending) lets the 5 c-sums share
// 32 acc VGPRs. Mask transposed once per block to tb[h] bits in LDS
// (broadcast reads only => ~0 bank conflicts).
// Wave = 8 b x 256 v (float4/lane); block = 256 thr = 2 bgrp x 2 vhalf
// = 16 b x 512 v; grid = 1024. W (2.6MB) L2-resident.
// Add order per (b,c,v) unchanged: h-ascending, zero-adds exact => bit
// identical.
// Semantics FROZEN (rounds 6-10 passed, absmax=0):
//  - threefry2x32 partitionable; fold-like split; seed(42)->(0,42).
//  - cephes-Horner exp, Pommier-Horner log (q1/q2 tail), no contract.
//  - sigmoid = 1/(1+exp(-x)) IEEE div; gumbel tiny-clamp; first-max
//    argmax; bernoulli u<p; v-GEMM K=256 single sequential chain.
//  - h-GEMM: Eigen gebp kc=320 slab fold, k ascending (c-major).
// ws layout unchanged (Wv region now unused); sentinel reads back
// ws_size as absmax=100+MB if short.
// =====================================================================

#define B_DIM 16384
#define C_DIM 5
#define H_DIM 256
#define V_DIM 512
#define KC    320   // Eigen MT gebp kc (Zen5 48KB L1d: min(435,320)=320)

struct TFOut { uint32_t a, b; };

typedef float f32x2 __attribute__((ext_vector_type(2)));

#if __has_builtin(__builtin_elementwise_fma)
#define PKFMA(A, B, C) __builtin_elementwise_fma((A), (B), (C))
#else
static __device__ inline f32x2 pkfma_(f32x2 a, f32x2 b, f32x2 c) {
  f32x2 r; r.x = fmaf(a.x, b.x, c.x); r.y = fmaf(a.y, b.y, c.y); return r;
}
#define PKFMA(A, B, C) pkfma_((A), (B), (C))
#endif

__host__ __device__ static inline TFOut tf2x32(uint32_t k0, uint32_t k1,
                                               uint32_t c0, uint32_t c1) {
  uint32_t ks2 = k0 ^ k1 ^ 0x1BD11BDAu;
  uint32_t x0 = c0 + k0, x1 = c1 + k1;
#define TF_R(r) { x0 += x1; x1 = (x1 << r) | (x1 >> (32 - r)); x1 ^= x0; }
  TF_R(13) TF_R(15) TF_R(26) TF_R(6)
  x0 += k1;  x1 += ks2 + 1u;
  TF_R(17) TF_R(29) TF_R(16) TF_R(24)
  x0 += ks2; x1 += k0 + 2u;
  TF_R(13) TF_R(15) TF_R(26) TF_R(6)
  x0 += k0;  x1 += k1 + 3u;
  TF_R(17) TF_R(29) TF_R(16) TF_R(24)
  x0 += k1;  x1 += ks2 + 4u;
  TF_R(13) TF_R(15) TF_R(26) TF_R(6)
  x0 += ks2; x1 += k0 + 5u;
#undef TF_R
  TFOut o; o.a = x0; o.b = x1; return o;
}

// partitionable random_bits, 32-bit width, element index i (< 2^32)
__device__ static inline uint32_t rng_bits(uint32_t k0, uint32_t k1, uint32_t i) {
  TFOut r = tf2x32(k0, k1, 0u, i);
  return r.a ^ r.b;
}

__device__ static inline float bits_to_unit_float(uint32_t bits) {
  return __uint_as_float((bits >> 9) | 0x3F800000u) - 1.0f;
}

// XLA GenerateVF32Exp replica (cephes Horner port), mul+add separate,
// NO contraction.
__device__ static float xla_exp(float x_in) {
#pragma clang fp contract(off)
  float x = fminf(x_in, 88.3762626647950f);
  x = fmaxf(x, -88.3762626647949f);
  float fx = floorf(x * 1.44269504088896341f + 0.5f);
  float tmp = fx * 0.693359375f;
  float z = fx * -2.12194440e-4f;
  x = x - tmp;
  x = x - z;
  z = x * x;
  float y = 1.9875691500e-4f;
  y = y * x + 1.3981999507e-3f;
  y = y * x + 8.3334519073e-3f;
  y = y * x + 4.1665795894e-2f;
  y = y * x + 1.6666665459e-1f;
  y = y * x + 5.0000001201e-1f;
  y = y * z + x;
  y = y + 1.0f;
  int n = (int)fx;
  y = y * __uint_as_float((uint32_t)(n + 127) << 23);
  return y;
}

// XLA GenerateVF32Log replica = Pommier/Eigen3.3 log_ps (Horner + tail:
// y+=e*q1; y-=0.5*z; x+=y; x+=e*q2). NO contraction.
__device__ static float xla_log(float x_in) {
#pragma clang fp contract(off)
  float xv = fmaxf(x_in, 1.17549435e-38f);      // min_norm_pos clamp
  uint32_t bits = __float_as_uint(xv);
  float e = (float)((int)(bits >> 23) - 126);
  float x = __uint_as_float((bits & 0x007FFFFFu) | 0x3F000000u);  // [0.5,1)
  bool m = (x < 0.707106781186547524f);
  float tmp = m ? x : 0.0f;
  x = x - 1.0f;
  e = e - (m ? 1.0f : 0.0f);
  x = x + tmp;
  float z = x * x;
  float y = 7.0376836292e-2f;
  y = y * x + -1.1514610310e-1f;
  y = y * x + 1.1676998740e-1f;
  y = y * x + -1.2420140846e-1f;
  y = y * x + 1.4249322787e-1f;
  y = y * x + -1.6668057665e-1f;
  y = y * x + 2.0000714765e-1f;
  y = y * x + -2.4999993993e-1f;
  y = y * x + 3.3333331174e-1f;
  y = y * x;
  y = y * z;
  float t1 = e * -2.12194440e-4f;
  y = y + t1;
  float t2 = z * 0.5f;
  y = y - t2;
  x = x + y;
  float t3 = e * 0.693359375f;
  x = x + t3;
  return x;
}

// ---------------- kernels ----------------

__global__ void k_sentinel(float* out, float d) {
  out[0] = d;
}

// v0 one-hot (B,C,V) -> idx (B,V) u8
__global__ __launch_bounds__(256) void k_idx(const float* __restrict__ v0,
                                             uint8_t* __restrict__ idx) {
  int t = blockIdx.x * 256 + threadIdx.x;          // b*V + v
  int b = t >> 9, v = t & 511;
  const float* p = v0 + (size_t)b * (C_DIM * V_DIM) + v;
  int cf = 0;
#pragma unroll
  for (int c = 0; c < C_DIM; ++c)
    if (p[c * V_DIM] > 0.5f) cf = c;
  idx[t] = (uint8_t)cf;
}

// W (c,h,v) -> Wt (c,v,h)
__global__ __launch_bounds__(256) void k_wt(const float* __restrict__ W,
                                            float* __restrict__ Wt) {
  int t = blockIdx.x * 256 + threadIdx.x;          // (c, v, h)
  int h = t & 255; int rest = t >> 8; int v = rest & 511; int c = rest >> 9;
  Wt[t] = W[((size_t)c * H_DIM + h) * V_DIM + v];
}

// h = bernoulli(sigmoid(kc-slab-folded k-ascending sum + c1))
// In-LDS compaction (round 7): soff[512] = selected k offsets asc,
// jb[s] = kc-panel boundaries. Order bit-identical to round 6.
__global__ __launch_bounds__(256) void k_sample_h(
    const float* __restrict__ Wt, const float* __restrict__ c1,
    const uint8_t* __restrict__ idx,
    float* __restrict__ out_h, uint32_t* __restrict__ out_mask,
    uint32_t key0, uint32_t key1) {
  __shared__ uint8_t  sidx[V_DIM];
  __shared__ uint32_t soff[V_DIM];     // (c*512+v)*1024 byte offsets, k asc
  __shared__ uint16_t cnt[8][5];       // per 64-lane segment, per class
  __shared__ uint16_t base[8][5];      // global start position
  __shared__ uint16_t jb[10];          // panel boundaries in j-space
  int b = blockIdx.x;
  int t = threadIdx.x;
  if (t < 128)
    ((uint32_t*)sidx)[t] = ((const uint32_t*)(idx + (size_t)b * V_DIM))[t];
  __syncthreads();

  int lane = t & 63, wv = t >> 6;
  int v0 = t,       c0 = sidx[v0];
  int v1 = t + 256, c1i = sidx[v1];
  int rank0, rank1;
  {
    unsigned long long bal[5];
#pragma unroll
    for (int cc = 0; cc < 5; ++cc) bal[cc] = __ballot(c0 == cc);
    if (lane == 0) {
#pragma unroll
      for (int cc = 0; cc < 5; ++cc) cnt[wv][cc] = (uint16_t)__popcll(bal[cc]);
    }
    rank0 = (int)__popcll(bal[c0] & ((1ull << lane) - 1ull));
  }
  {
    unsigned long long bal[5];
#pragma unroll
    for (int cc = 0; cc < 5; ++cc) bal[cc] = __ballot(c1i == cc);
    if (lane == 0) {
#pragma unroll
      for (int cc = 0; cc < 5; ++cc) cnt[4 + wv][cc] = (uint16_t)__popcll(bal[cc]);
    }
    rank1 = (int)__popcll(bal[c1i] & ((1ull << lane) - 1ull));
  }
  __syncthreads();
  if (t == 0) {
    int pos = 0;
    for (int cc = 0; cc < 5; ++cc)
      for (int g = 0; g < 8; ++g) { base[g][cc] = (uint16_t)pos; pos += cnt[g][cc]; }
  }
  __syncthreads();
  soff[base[wv][c0] + rank0]       = (uint32_t)(c0 * V_DIM + v0) << 10;   // k*1024B
  soff[base[4 + wv][c1i] + rank1]  = (uint32_t)(c1i * V_DIM + v1) << 10;
  __syncthreads();
  if (t < 10) {
    uint32_t target = (uint32_t)(t * KC) << 10;
    int lo = 0, hi = V_DIM;
    while (lo < hi) { int mid = (lo + hi) >> 1;
      if (soff[mid] < target) lo = mid + 1; else hi = mid; }
    jb[t] = (uint16_t)lo;
  }
  __syncthreads();

  // main accumulation: h = t
  const char* Wh = (const char*)Wt + (size_t)t * 4;
  float total = 0.0f;
  for (int s = 0; s < 9; ++s) {
    int j = jb[s], jend = jb[s + 1];
    float psum = 0.0f;
    for (; j + 4 <= jend; j += 4) {
      float w0 = *(const float*)(Wh + soff[j]);
      float w1 = *(const float*)(Wh + soff[j + 1]);
      float w2 = *(const float*)(Wh + soff[j + 2]);
      float w3 = *(const float*)(Wh + soff[j + 3]);
      psum += w0; psum += w1; psum += w2; psum += w3;
    }
    for (; j < jend; ++j) psum += *(const float*)(Wh + soff[j]);
    total += psum;
  }

  float tt = total + c1[t];
  float p = 1.0f / (1.0f + xla_exp(-tt));   // IEEE div, logistic exp form

  uint32_t i = (uint32_t)(b * H_DIM + t);
  float u = bits_to_unit_float(rng_bits(key0, key1, i));
  bool hb = (u < p);
  if (out_h) out_h[(size_t)b * H_DIM + t] = hb ? 1.0f : 0.0f;

  unsigned long long m = __ballot(hb);
  if ((t & 63) == 0) {
    out_mask[(size_t)b * 8 + wv * 2 + 0] = (uint32_t)(m & 0xFFFFFFFFull);
    out_mask[(size_t)b * 8 + wv * 2 + 1] = (uint32_t)(m >> 32);
  }
}

// v = categorical over c of (h-ascending dense fma sum + b2 + gumbel).
// h-major: per (c,h) the W row is loaded once, coalesced (1024B/wave),
// shared across 8 register-resident b's:  acc = fma(w, f, acc),
// f = (float)bit in {0,1} -- bit-exact vs sequential chain with skips.
// Per-c running first-max argmax (c ascending) reuses acc registers.
// Wave = 8 b x 256 v; block = 256 thr (2 bgrp x 2 vhalf) = 16 b.
#define ACC_H(BITS, W4)                                              \
  {                                                                  \
    f32x2 w01 = {(W4).x, (W4).y}, w23 = {(W4).z, (W4).w};            \
    uint32_t bits_ = (BITS) >> (bgrp * 8);                           \
    _Pragma("unroll")                                                \
    for (int i = 0; i < 8; ++i) {                                    \
      float f = (float)((bits_ >> i) & 1u);                          \
      f32x2 ff = {f, f};                                             \
      a01[i] = PKFMA(w01, ff, a01[i]);                               \
      a23[i] = PKFMA(w23, ff, a23[i]);                               \
    }                                                                \
  }

__global__ __launch_bounds__(256, 4) void k_sample_v(
    const float* __restrict__ W, const float* __restrict__ b2,
    const uint32_t* __restrict__ mask, uint8_t* __restrict__ idx_out,
    uint32_t key0, uint32_t key1) {
  __shared__ uint32_t smask[16][8];
  __shared__ __align__(16) uint32_t tb[H_DIM];   // bit j of tb[h] = h-bit of b0+j
  int tid = threadIdx.x;
  int b0 = blockIdx.x * 16;

  if (tid < 128) smask[tid >> 3][tid & 7] = mask[(size_t)b0 * 8 + tid];
  __syncthreads();
  {
    int h = tid;                       // 256 threads = 256 h's
    uint32_t w = (uint32_t)(h >> 5), s = (uint32_t)(h & 31), x = 0;
#pragma unroll
    for (int j = 0; j < 16; ++j)
      x |= ((smask[j][w] >> s) & 1u) << j;
    tb[h] = x;
  }
  __syncthreads();

  int wv = tid >> 6, lane = tid & 63;
  int bgrp = wv & 1, vhalf = wv >> 1;
  int b_base = b0 + bgrp * 8;
  int v0 = vhalf * 256 + lane * 4;

  float best[8][4];
  uint32_t bc[8];
#pragma unroll
  for (int i = 0; i < 8; ++i) bc[i] = 0u;

  const uint4* tbv = (const uint4*)tb;

  for (int c = 0; c < C_DIM; ++c) {
    f32x2 a01[8], a23[8];
#pragma unroll
    for (int i = 0; i < 8; ++i) {
      a01[i] = (f32x2){0.0f, 0.0f};
      a23[i] = (f32x2){0.0f, 0.0f};
    }
    const float* wp = W + (size_t)c * (H_DIM * V_DIM) + v0;
    uint4 qn = tbv[0];
    for (int h4 = 0; h4 < 64; ++h4) {
      uint4 qq = qn;
      if (h4 < 63) qn = tbv[h4 + 1];       // prefetch next bits early
      float4 w0 = *(const float4*)(wp);
      float4 w1 = *(const float4*)(wp + V_DIM);
      float4 w2 = *(const float4*)(wp + 2 * V_DIM);
      float4 w3 = *(const float4*)(wp + 3 * V_DIM);
      wp += 4 * V_DIM;
      ACC_H(qq.x, w0)
      ACC_H(qq.y, w1)
      ACC_H(qq.z, w2)
      ACC_H(qq.w, w3)
    }

    // epilogue for this c: gumbel + running first-max argmax (c asc)
    float4 bv = *(const float4*)(b2 + c * V_DIM + v0);
    float bb0 = bv.x, bb1 = bv.y, bb2 = bv.z, bb3 = bv.w;
#pragma unroll
    for (int i = 0; i < 8; ++i) {
      uint32_t ib = ((uint32_t)(b_base + i) * C_DIM + (uint32_t)c) * V_DIM
                    + (uint32_t)v0;
      float av[4] = {a01[i].x, a01[i].y, a23[i].x, a23[i].y};
      float bbq[4] = {bb0, bb1, bb2, bb3};
#pragma unroll
      for (int q = 0; q < 4; ++q) {
        float uf = bits_to_unit_float(rng_bits(key0, key1, ib + (uint32_t)q));
        if (uf == 0.0f) uf = 1.17549435e-38f;        // u + tiny semantics
        float g = -xla_log(-xla_log(uf));
        float z = g + (av[q] + bbq[q]);
        if (c == 0 || z > best[i][q]) {
          best[i][q] = z;
          bc[i] = (bc[i] & ~(0xFFu << (8 * q))) | ((uint32_t)c << (8 * q));
        }
      }
    }
  }

#pragma unroll
  for (int i = 0; i < 8; ++i)
    *(uint32_t*)(idx_out + (size_t)(b_base + i) * V_DIM + v0) = bc[i];
}

// idx -> one-hot f32 (B,C,V)
__global__ __launch_bounds__(256) void k_onehot(const uint8_t* __restrict__ idx,
                                                float* __restrict__ out) {
  int t = blockIdx.x * 256 + threadIdx.x;     // b*C*V + c*V + v
  int v = t & 511; int rest = t >> 9; int c = rest % C_DIM; int b = rest / C_DIM;
  out[t] = (idx[(size_t)b * V_DIM + v] == c) ? 1.0f : 0.0f;
}

// ---------------- launch ----------------

extern "C" void kernel_launch(void* const* d_in, const int* in_sizes, int n_in,
                              void* d_out, int out_size, void* d_ws, size_t ws_size,
                              hipStream_t stream) {
  float* out = (float*)d_out;

  // ---- structural sentinels ----
  const size_t WS_NEED = 2621440ull      // Wt
                       + 2621440ull      // (ex-Wv, unused, layout kept)
                       + 8388608ull      // idx
                       + 524288ull;      // mask  = 14,155,776 B
  float D = 0.0f;
  if (n_in < 4)                       D = 910.0f + (float)n_in;
  else if (in_sizes[0] != 41943040)   D = 920.0f;
  else if (in_sizes[1] != 655360)     D = 921.0f;
  else if (in_sizes[2] != 2560)       D = 922.0f;
  else if (in_sizes[3] != 256)        D = 923.0f;
  else if (out_size != 50331648)      D = 930.0f + (float)out_size * 1e-6f;
  else if (ws_size < WS_NEED)         D = 100.0f + (float)(ws_size >> 20);
  if (D != 0.0f) {
    hipLaunchKernelGGL(k_sentinel, dim3(1), dim3(1), 0, stream, out, D);
    return;
  }

  const float* v0 = (const float*)d_in[0];
  const float* W  = (const float*)d_in[1];
  const float* b2 = (const float*)d_in[2];   // (C,V)
  const float* c1 = (const float*)d_in[3];   // (H)

  float* out_v  = out;                                         // B*C*V
  float* out_h  = out + (size_t)B_DIM * C_DIM * V_DIM;         // B*H (final h)
  float* out_h0 = out_h + (size_t)B_DIM * H_DIM;               // B*H (h|v0)

  char* ws = (char*)d_ws;
  float*    Wt   = (float*)(ws);                    // 2,621,440 B
  uint8_t*  idx  = (uint8_t*)(ws + 5242880);        // 8,388,608 B
  uint32_t* mask = (uint32_t*)(ws + 13631488);      //   524,288 B

  // partitionable (fold-like) split of key(42) into 5 subkeys
  uint32_t keys[5][2];
  for (int i = 0; i < 5; ++i) {
    TFOut r = tf2x32(0u, 42u, 0u, (uint32_t)i);
    keys[i][0] = r.a; keys[i][1] = r.b;
  }

  hipLaunchKernelGGL(k_wt,  dim3(2560),  dim3(256), 0, stream, W, Wt);
  hipLaunchKernelGGL(k_idx, dim3(32768), dim3(256), 0, stream, v0, idx);

  // h0 = sample_h(keys[0], v0) -> h_given_v0 output + mask
  hipLaunchKernelGGL(k_sample_h, dim3(B_DIM), dim3(256), 0, stream,
                     Wt, c1, idx, out_h0, mask, keys[0][0], keys[0][1]);
  // iter 0: v = sample_v(keys[1], h0); h1 = sample_h(keys[2], v)
  hipLaunchKernelGGL(k_sample_v, dim3(B_DIM / 16), dim3(256), 0, stream,
                     W, b2, mask, idx, keys[1][0], keys[1][1]);
  hipLaunchKernelGGL(k_sample_h, dim3(B_DIM), dim3(256), 0, stream,
                     Wt, c1, idx, (float*)nullptr, mask, keys[2][0], keys[2][1]);
  // iter 1: v = sample_v(keys[3], h1); h2 = sample_h(keys[4], v)
  hipLaunchKernelGGL(k_sample_v, dim3(B_DIM / 16), dim3(256), 0, stream,
                     W, b2, mask, idx, keys[3][0], keys[3][1]);
  hipLaunchKernelGGL(k_sample_h, dim3(B_DIM), dim3(256), 0, stream,
                     Wt, c1, idx, out_h, mask, keys[4][0], keys[4][1]);
  // final v one-hot output
  hipLaunchKernelGGL(k_onehot, dim3(163840), dim3(256), 0, stream, idx, out_v);
}